// Round 7
// baseline (6591.126 us; speedup 1.0000x reference)
//
#include <hip/hip_runtime.h>
#include <math.h>

#define NITEMS 50000
#define NROWS 50001
#define NP 50048          // padded column count for transposed feat
#define DD 512
#define HH 512
#define TT 16
#define NEGV (-1e18f)
#define NGRP 782          // 50048/64 row-groups for attnT
#define HOPBLK 2048       // hop grid blocks (x4 waves = 8192 waves)

typedef unsigned long long ull;
typedef float f32x2 __attribute__((ext_vector_type(2)));

// ---- order-preserving float <-> uint key ----
__device__ __forceinline__ unsigned fkey(float f) {
  unsigned u = __float_as_uint(f);
  return (u & 0x80000000u) ? ~u : (u | 0x80000000u);
}

// fast tanh / exp via v_exp_f32 + v_rcp_f32
__device__ __forceinline__ float ftanh(float x) {
  float e = __builtin_amdgcn_exp2f(x * 2.885390081777927f);  // exp(2x)
  return 1.f - 2.f * __builtin_amdgcn_rcpf(e + 1.f);
}
__device__ __forceinline__ float fexp(float x) {
  return __builtin_amdgcn_exp2f(x * 1.4426950408889634f);
}

// packed fp32 FMA: d.lo += a.lo*b.lo ; d.hi += a.hi*b.lo   (b.lo broadcast)
__device__ __forceinline__ void pkfma_blo(f32x2& d, f32x2 a, f32x2 b) {
  asm("v_pk_fma_f32 %0, %1, %2, %0 op_sel:[0,0,0] op_sel_hi:[1,0,1]"
      : "+v"(d) : "v"(a), "v"(b));
}
// packed fp32 FMA: d.lo += a.lo*b.hi ; d.hi += a.hi*b.hi   (b.hi broadcast)
__device__ __forceinline__ void pkfma_bhi(f32x2& d, f32x2 a, f32x2 b) {
  asm("v_pk_fma_f32 %0, %1, %2, %0 op_sel:[0,1,0] op_sel_hi:[1,1,1]"
      : "+v"(d) : "v"(a), "v"(b));
}

// ---------------- feat = mem @ W ; TR=1 stores transposed [n][m] (NP-padded) ----------------
// 128x128 tile, BK=8, 256 threads; 8x8 microtile as 4x8 row-pair f32x2 accs via v_pk_fma_f32.
// Bijective XCD-chunk swizzle: 4 n-tiles of an A-panel stay on one XCD (L2 A-reuse).
template <int TR>
__launch_bounds__(256)
__global__ void k_feat_gemm(const float* __restrict__ A0, const float* __restrict__ stoprow,
                            const float* __restrict__ B, float* __restrict__ C) {
  __shared__ float As[8][128];
  __shared__ float Bs[8][128];
  const int tid = threadIdx.x;
  // ---- XCD swizzle (total 1564 = 391*4 blocks; q=195, r=4) ----
  const int lid = blockIdx.y * 4 + blockIdx.x;
  const int xcd = lid & 7, pos = lid >> 3;
  const int orig = ((xcd < 4) ? xcd * 196 : 784 + (xcd - 4) * 195) + pos;
  const int m0 = (orig >> 2) * 128, n0 = (orig & 3) * 128;

  const int tx = tid & 15, ty = tid >> 4;
  const int ar = tid >> 1, ak = (tid & 1) * 4;
  const int bk = tid >> 5, bc = (tid & 31) * 4;
  const int arow = m0 + ar;
  const float* Arow = (arow < NITEMS) ? (A0 + (size_t)arow * DD) : stoprow;
  const bool avalid = (arow < NROWS);
  f32x2 acc2[4][8];
#pragma unroll
  for (int i = 0; i < 4; ++i)
#pragma unroll
    for (int j = 0; j < 8; ++j) acc2[i][j] = (f32x2){0.f, 0.f};

  for (int kt = 0; kt < DD; kt += 8) {
    float4 av = avalid ? *(const float4*)(Arow + kt + ak) : make_float4(0.f, 0.f, 0.f, 0.f);
    As[ak + 0][ar] = av.x;
    As[ak + 1][ar] = av.y;
    As[ak + 2][ar] = av.z;
    As[ak + 3][ar] = av.w;
    *(float4*)&Bs[bk][bc] = *(const float4*)(B + (size_t)(kt + bk) * HH + n0 + bc);
    __syncthreads();
#pragma unroll
    for (int k = 0; k < 8; ++k) {
      const f32x2* ap = (const f32x2*)&As[k][ty * 8];   // 4 natural row-pairs
      const f32x2* bp0 = (const f32x2*)&Bs[k][tx * 4];  // cols tx*4..+3
      const f32x2* bp1 = (const f32x2*)&Bs[k][64 + tx * 4];
      f32x2 a2[4] = {ap[0], ap[1], ap[2], ap[3]};
      f32x2 b2[4] = {bp0[0], bp0[1], bp1[0], bp1[1]};
#pragma unroll
      for (int ii = 0; ii < 4; ++ii) {
#pragma unroll
        for (int jj = 0; jj < 4; ++jj) {
          pkfma_blo(acc2[ii][2 * jj], a2[ii], b2[jj]);      // col: base + 0
          pkfma_bhi(acc2[ii][2 * jj + 1], a2[ii], b2[jj]);  // col: base + 1
        }
      }
    }
    __syncthreads();
  }
  // acc2[ii][c]: rows (ty*8+2ii, +1) in (.x,.y); col c: c<4 -> tx*4+c%... mapping below
  // col(c) = (c<2? tx*4 + c : c<4 ? tx*4 + c : 64 + tx*4 + (c-4))  [c=0..3 -> tx*4+c; c=4..7 -> 64+tx*4+c-4]
  if (TR) {
#pragma unroll
    for (int c = 0; c < 8; ++c) {
      const int n = (c < 4) ? (n0 + tx * 4 + c) : (n0 + 64 + tx * 4 + (c - 4));
      float* cp = C + (size_t)n * NP + m0 + ty * 8;
      *(float4*)cp = make_float4(acc2[0][c].x, acc2[0][c].y, acc2[1][c].x, acc2[1][c].y);
      *(float4*)(cp + 4) = make_float4(acc2[2][c].x, acc2[2][c].y, acc2[3][c].x, acc2[3][c].y);
    }
  } else {
#pragma unroll
    for (int ii = 0; ii < 4; ++ii) {
#pragma unroll
      for (int half = 0; half < 2; ++half) {
        const int row = m0 + ty * 8 + 2 * ii + half;
        if (row < NROWS) {
          float* crow = C + (size_t)row * HH + n0;
          if (half == 0) {
            *(float4*)(crow + tx * 4) =
                make_float4(acc2[ii][0].x, acc2[ii][1].x, acc2[ii][2].x, acc2[ii][3].x);
            *(float4*)(crow + 64 + tx * 4) =
                make_float4(acc2[ii][4].x, acc2[ii][5].x, acc2[ii][6].x, acc2[ii][7].x);
          } else {
            *(float4*)(crow + tx * 4) =
                make_float4(acc2[ii][0].y, acc2[ii][1].y, acc2[ii][2].y, acc2[ii][3].y);
            *(float4*)(crow + 64 + tx * 4) =
                make_float4(acc2[ii][4].y, acc2[ii][5].y, acc2[ii][6].y, acc2[ii][7].y);
          }
        }
      }
    }
  }
}

// ---------------- zero sel ----------------
__global__ void k_zero(int* __restrict__ sel) {
  int i = blockIdx.x * 256 + threadIdx.x;
  if (i < NROWS) sel[i] = 0;
}

// ---------------- finalize prev step (redundant in all blocks) + LSTM gates ----------------
__launch_bounds__(256)
__global__ void k_final_gates(const float* __restrict__ bma, const float* __restrict__ bZa,
                              const ull* __restrict__ bkey, const float* __restrict__ sc,
                              int* __restrict__ sel, int* __restrict__ done2,
                              int* __restrict__ xrow2, float* __restrict__ outf,
                              const float* __restrict__ attn_mem, const float* __restrict__ stoprow,
                              const float* __restrict__ init_i, const float* __restrict__ init_h,
                              const float* __restrict__ hv,
                              const float* __restrict__ w_ih, const float* __restrict__ w_hh,
                              const float* __restrict__ b_ih, const float* __restrict__ b_hh,
                              float* __restrict__ gates, int t) {
  __shared__ float redm[256], redz[256];
  __shared__ ull redk[256];
  const int tid = threadIdx.x, blk = blockIdx.x;
  const int w = tid >> 6, lane = tid & 63;
  int xrow = -1;
  if (t > 0) {
    float Ml = -3.0e38f;
    ull Kl = 0;
    for (int i = tid; i < NGRP; i += 256) {
      Ml = fmaxf(Ml, bma[i]);
      ull k = bkey[i];
      if (k > Kl) Kl = k;
    }
    redm[tid] = Ml;
    redk[tid] = Kl;
    __syncthreads();
    for (int s2 = 128; s2 > 0; s2 >>= 1) {
      if (tid < s2) {
        redm[tid] = fmaxf(redm[tid], redm[tid + s2]);
        if (redk[tid + s2] > redk[tid]) redk[tid] = redk[tid + s2];
      }
      __syncthreads();
    }
    const float M = redm[0];
    const ull K = redk[0];
    __syncthreads();
    float Zl = 0.f;
    for (int i = tid; i < NGRP; i += 256) Zl += bZa[i] * expf(bma[i] - M);
    redz[tid] = Zl;
    __syncthreads();
    for (int s2 = 128; s2 > 0; s2 >>= 1) {
      if (tid < s2) redz[tid] += redz[tid + s2];
      __syncthreads();
    }
    const float Z = redz[0];
    const int out = NITEMS - (int)(unsigned)(K & 0xffffffffull);
    const int d_in = (t == 1) ? 0 : done2[(t - 1) & 1];
    const int xprev = (t == 1) ? -1 : xrow2[(t - 1) & 1];
    const int nd = d_in | (out == NITEMS);
    xrow = nd ? xprev : out;
    if (blk == 0 && tid == 0) {
      outf[t - 1] = (float)(d_in ? NITEMS : out);
      outf[TT + t - 1] = d_in ? 0.f : (sc[out] - M - logf(Z));
      if (!d_in) sel[out] = 1;
      done2[t & 1] = nd;
      xrow2[t & 1] = xrow;
    }
  }
  // LSTM gate row r = blk*4 + w  (512 blocks x 4 waves = 2048 rows)
  const int r = blk * 4 + w;
  const float* xp = (xrow < 0) ? init_i
                               : ((xrow == NITEMS) ? stoprow : attn_mem + (size_t)xrow * DD);
  const float* hp = (t == 0) ? init_h : hv;
  const float4* x4 = (const float4*)xp;
  const float4* h4 = (const float4*)hp;
  const float4* wi = (const float4*)(w_ih + (size_t)r * DD);
  const float4* wh = (const float4*)(w_hh + (size_t)r * DD);
  float s = 0.f;
  float4 a, ww;
  a = x4[lane * 2];     ww = wi[lane * 2];     s += a.x * ww.x + a.y * ww.y + a.z * ww.z + a.w * ww.w;
  a = x4[lane * 2 + 1]; ww = wi[lane * 2 + 1]; s += a.x * ww.x + a.y * ww.y + a.z * ww.z + a.w * ww.w;
  a = h4[lane * 2];     ww = wh[lane * 2];     s += a.x * ww.x + a.y * ww.y + a.z * ww.z + a.w * ww.w;
  a = h4[lane * 2 + 1]; ww = wh[lane * 2 + 1]; s += a.x * ww.x + a.y * ww.y + a.z * ww.z + a.w * ww.w;
#pragma unroll
  for (int off = 32; off > 0; off >>= 1) s += __shfl_xor(s, off);
  if (lane == 0) gates[r] = s + b_ih[r] + b_hh[r];
}

// ---------------- h,c update (redundant x8) + b1 = h @ hop_wq ----------------
__launch_bounds__(256)
__global__ void k_hc_b1(const float* __restrict__ gates, const float* __restrict__ init_c,
                        float* __restrict__ cv0, float* __restrict__ cv1, float* __restrict__ hv,
                        const float* __restrict__ hop_wq, float* __restrict__ b1, int t) {
  __shared__ float h[512];
  __shared__ float red[256];
  const int tid = threadIdx.x, blk = blockIdx.x;
  const float* csrc = (t == 0) ? init_c : ((t & 1) ? cv1 : cv0);
  float* cdst = (t & 1) ? cv0 : cv1;
  for (int i = tid; i < 512; i += 256) {
    float gi = gates[i], gf = gates[512 + i], gg = gates[1024 + i], go = gates[1536 + i];
    float si = 1.f / (1.f + expf(-gi));
    float sf = 1.f / (1.f + expf(-gf));
    float so = 1.f / (1.f + expf(-go));
    float cn = sf * csrc[i] + si * tanhf(gg);
    float hval = so * tanhf(cn);
    h[i] = hval;
    if (blk == 0) { cdst[i] = cn; hv[i] = hval; }
  }
  __syncthreads();
  const int cc = tid & 63, q = tid >> 6;
  const int j = blk * 64 + cc;
  float pb = 0.f;
  for (int i = q * 128; i < q * 128 + 128; ++i) pb = fmaf(h[i], hop_wq[(size_t)i * HH + j], pb);
  red[tid] = pb;
  __syncthreads();
  if (tid < 64) b1[blk * 64 + tid] = red[tid] + red[tid + 64] + red[tid + 128] + red[tid + 192];
}

// ---------------- hop: fused score + online-softmax weighted sum (8192 waves) ----------------
__launch_bounds__(256)
__global__ void k_hop(const float* __restrict__ feat, const float* __restrict__ bvec,
                      const float* __restrict__ v, float* __restrict__ qp,
                      float* __restrict__ bmh, float* __restrict__ bZh) {
  __shared__ float smax[4], sz[4];
  __shared__ float qbuf[4][512];
  const int tid = threadIdx.x, blk = blockIdx.x;
  const int w = tid >> 6, lane = tid & 63;
  const int wv = blk * 4 + w;
  float bv[8], vv[8], qa[8];
#pragma unroll
  for (int j = 0; j < 8; ++j) { bv[j] = bvec[lane * 8 + j]; vv[j] = v[lane * 8 + j]; qa[j] = 0.f; }
  float M = -3.0e38f, Z = 0.f;
  for (int m = wv; m < NROWS; m += 4 * HOPBLK) {
    const float4* fp = (const float4*)(feat + (size_t)m * HH);
    float4 A = fp[lane * 2], B = fp[lane * 2 + 1];
    float f[8] = {A.x, A.y, A.z, A.w, B.x, B.y, B.z, B.w};
    float s = 0.f;
#pragma unroll
    for (int j = 0; j < 8; ++j) s += ftanh(f[j] + bv[j]) * vv[j];
#pragma unroll
    for (int off = 32; off > 0; off >>= 1) s += __shfl_xor(s, off);
    const float Mn = fmaxf(M, s);
    const float scale = fexp(M - Mn), e = fexp(s - Mn);
    Z = Z * scale + e;
#pragma unroll
    for (int j = 0; j < 8; ++j) qa[j] = fmaf(e, f[j], qa[j] * scale);
    M = Mn;
  }
  if (lane == 0) { smax[w] = M; sz[w] = Z; }
  __syncthreads();
  float Mb = fmaxf(fmaxf(smax[0], smax[1]), fmaxf(smax[2], smax[3]));
  const float sw = fexp(M - Mb);
#pragma unroll
  for (int j = 0; j < 8; ++j) qbuf[w][lane * 8 + j] = qa[j] * sw;
  __syncthreads();
  float a0 = 0.f, a1 = 0.f;
#pragma unroll
  for (int w2 = 0; w2 < 4; ++w2) { a0 += qbuf[w2][tid]; a1 += qbuf[w2][tid + 256]; }
  qp[(size_t)blk * 512 + tid] = a0;
  qp[(size_t)blk * 512 + tid + 256] = a1;
  if (tid == 0) {
    float Zb = 0.f;
#pragma unroll
    for (int w2 = 0; w2 < 4; ++w2) Zb += sz[w2] * expf(smax[w2] - Mb);
    bmh[blk] = Mb;
    bZh[blk] = Zb;
  }
}

// ---------------- merged: combine 2048 hop partials -> qn -> b2 = qn @ attn_wq ----------------
// 8 blocks x 1024 threads; each block redundantly combines, then computes its 64 b2 columns.
__launch_bounds__(1024)
__global__ void k_qn_b2(const float* __restrict__ qp, const float* __restrict__ bmh,
                        const float* __restrict__ bZh, const float* __restrict__ attn_wq,
                        float* __restrict__ b2) {
  __shared__ float red[1024];
  __shared__ float cf[HOPBLK];
  __shared__ float qn_s[512];
  const int tid = threadIdx.x, blk = blockIdx.x;
  red[tid] = fmaxf(bmh[tid], bmh[tid + 1024]);
  __syncthreads();
  for (int s2 = 512; s2 > 0; s2 >>= 1) {
    if (tid < s2) red[tid] = fmaxf(red[tid], red[tid + s2]);
    __syncthreads();
  }
  const float Mg = red[0];
  __syncthreads();
  float c0 = expf(bmh[tid] - Mg), c1 = expf(bmh[tid + 1024] - Mg);
  cf[tid] = c0;
  cf[tid + 1024] = c1;
  red[tid] = bZh[tid] * c0 + bZh[tid + 1024] * c1;
  __syncthreads();
  for (int s2 = 512; s2 > 0; s2 >>= 1) {
    if (tid < s2) red[tid] += red[tid + s2];
    __syncthreads();
  }
  const float Z = red[0];
  __syncthreads();
  // qn: col = tid&511, half p-range = tid>>9
  {
    const int col = tid & 511, half = tid >> 9;
    float acc = 0.f;
    for (int p = half * 1024; p < half * 1024 + 1024; ++p)
      acc = fmaf(cf[p], qp[(size_t)p * 512 + col], acc);
    red[tid] = acc;
    __syncthreads();
    if (tid < 512) qn_s[tid] = (red[tid] + red[tid + 512]) / Z;
    __syncthreads();
  }
  // gemv: 64 cols for this block; 16 row-segments of 32
  {
    const int jj = tid & 63, seg = tid >> 6;
    const int j = blk * 64 + jj;
    float pb = 0.f;
    for (int i = seg * 32; i < seg * 32 + 32; ++i)
      pb = fmaf(qn_s[i], attn_wq[(size_t)i * HH + j], pb);
    red[tid] = pb;
    __syncthreads();
    if (tid < 64) {
      float a = 0.f;
#pragma unroll
      for (int s = 0; s < 16; ++s) a += red[tid + 64 * s];
      b2[blk * 64 + tid] = a;
    }
  }
}

// ---------------- attn: transposed sweep — 64 rows/wave-group, no per-row shuffles ----------------
__launch_bounds__(256)
__global__ void k_attnT(const float* __restrict__ featT, const float* __restrict__ b2,
                        const float* __restrict__ av, const int* __restrict__ sel,
                        const float* __restrict__ gum, float* __restrict__ sc,
                        float* __restrict__ bma, float* __restrict__ bZa, ull* __restrict__ bkey) {
  __shared__ float spart[4][64];
  const int tid = threadIdx.x, g = blockIdx.x;
  const int w = tid >> 6, lane = tid & 63;
  const int m = g * 64 + lane;   // < NP always (padded)
  const int h0 = w * 128;
  const float* fp = featT + (size_t)h0 * NP + m;
  float acc = 0.f;
#pragma unroll 8
  for (int hh = 0; hh < 128; ++hh) {
    float f = *fp;
    fp += NP;
    acc += ftanh(f + b2[h0 + hh]) * av[h0 + hh];
  }
  spart[w][lane] = acc;
  __syncthreads();
  if (w == 0) {
    float s = spart[0][lane] + spart[1][lane] + spart[2][lane] + spart[3][lane];
    const bool valid = (m < NROWS);
    float M, Z;
    ull key;
    if (valid) {
      float se = sel[m] ? NEGV : s;
      sc[m] = se;
      key = ((ull)fkey(se + gum[m]) << 32) | (unsigned)(NITEMS - m);
      M = se;
      Z = 1.f;
    } else {
      key = 0;
      M = -3.0e38f;
      Z = 0.f;
    }
#pragma unroll
    for (int off = 32; off > 0; off >>= 1) {
      float Mo = __shfl_xor(M, off);
      float Zo = __shfl_xor(Z, off);
      ull Ko = __shfl_xor(key, off);
      float Mn = fmaxf(M, Mo);
      Z = Z * fexp(M - Mn) + Zo * fexp(Mo - Mn);
      M = Mn;
      if (Ko > key) key = Ko;
    }
    if (lane == 0) { bma[g] = M; bZa[g] = Z; bkey[g] = key; }
  }
}

// ---------------- final outputs for step 15 ----------------
__launch_bounds__(256)
__global__ void k_tail(const float* __restrict__ bma, const float* __restrict__ bZa,
                       const ull* __restrict__ bkey, const float* __restrict__ sc,
                       const int* __restrict__ done2, float* __restrict__ outf) {
  __shared__ float redm[256], redz[256];
  __shared__ ull redk[256];
  const int tid = threadIdx.x;
  float Ml = -3.0e38f;
  ull Kl = 0;
  for (int i = tid; i < NGRP; i += 256) {
    Ml = fmaxf(Ml, bma[i]);
    ull k = bkey[i];
    if (k > Kl) Kl = k;
  }
  redm[tid] = Ml;
  redk[tid] = Kl;
  __syncthreads();
  for (int s2 = 128; s2 > 0; s2 >>= 1) {
    if (tid < s2) {
      redm[tid] = fmaxf(redm[tid], redm[tid + s2]);
      if (redk[tid + s2] > redk[tid]) redk[tid] = redk[tid + s2];
    }
    __syncthreads();
  }
  const float M = redm[0];
  const ull K = redk[0];
  __syncthreads();
  float Zl = 0.f;
  for (int i = tid; i < NGRP; i += 256) Zl += bZa[i] * expf(bma[i] - M);
  redz[tid] = Zl;
  __syncthreads();
  for (int s2 = 128; s2 > 0; s2 >>= 1) {
    if (tid < s2) redz[tid] += redz[tid + s2];
    __syncthreads();
  }
  if (tid == 0) {
    const float Z = redz[0];
    const int out = NITEMS - (int)(unsigned)(K & 0xffffffffull);
    const int d_in = done2[(TT - 1) & 1];
    outf[TT - 1] = (float)(d_in ? NITEMS : out);
    outf[2 * TT - 1] = d_in ? 0.f : (sc[out] - M - logf(Z));
  }
}

// ======================================================================
extern "C" void kernel_launch(void* const* d_in, const int* in_sizes, int n_in,
                              void* d_out, int out_size, void* d_ws, size_t ws_size,
                              hipStream_t stream) {
  const float* attn_mem = (const float*)d_in[0];
  const float* stoprow  = (const float*)d_in[1];
  const float* init_h   = (const float*)d_in[2];
  const float* init_c   = (const float*)d_in[3];
  const float* init_i   = (const float*)d_in[4];
  const float* attn_wm  = (const float*)d_in[5];
  const float* attn_wq  = (const float*)d_in[6];
  const float* attn_v   = (const float*)d_in[7];
  const float* hop_wm   = (const float*)d_in[8];
  const float* hop_wq   = (const float*)d_in[9];
  const float* hop_v    = (const float*)d_in[10];
  const float* w_ih     = (const float*)d_in[11];
  const float* w_hh     = (const float*)d_in[12];
  const float* b_ih     = (const float*)d_in[13];
  const float* b_hh     = (const float*)d_in[14];
  const float* gumbel   = (const float*)d_in[15];

  float* ws = (float*)d_ws;
  size_t fo = 0;
  float* hop_feat   = ws + fo; fo += (size_t)NROWS * HH;   // normal layout
  float* attn_featT = ws + fo; fo += (size_t)HH * NP;      // transposed, padded
  float* sc  = ws + fo; fo += 50048;
  int* sel   = (int*)(ws + fo); fo += 50048;
  float* qp  = ws + fo; fo += (size_t)HOPBLK * 512;
  float* bmh = ws + fo; fo += HOPBLK;
  float* bZh = ws + fo; fo += HOPBLK;
  float* bma = ws + fo; fo += 1024;
  float* bZa = ws + fo; fo += 1024;
  ull* bkey  = (ull*)(ws + fo); fo += 2048;
  float* gates = ws + fo; fo += 4 * HH;
  float* hv  = ws + fo; fo += HH;
  float* cv0 = ws + fo; fo += HH;
  float* cv1 = ws + fo; fo += HH;
  float* b1  = ws + fo; fo += HH;
  float* b2  = ws + fo; fo += HH;
  int* done2 = (int*)(ws + fo); fo += 2;
  int* xrow2 = (int*)(ws + fo); fo += 2;
  if (fo * sizeof(float) > ws_size) return;

  float* outf = (float*)d_out;

  k_zero<<<196, 256, 0, stream>>>(sel);
  dim3 ggrid(4, (NP + 127) / 128);  // 391 m-tiles x 4 n-tiles = 1564 blocks
  k_feat_gemm<1><<<ggrid, 256, 0, stream>>>(attn_mem, stoprow, attn_wm, attn_featT);
  k_feat_gemm<0><<<ggrid, 256, 0, stream>>>(attn_mem, stoprow, hop_wm, hop_feat);

  for (int t = 0; t < TT; ++t) {
    k_final_gates<<<512, 256, 0, stream>>>(bma, bZa, bkey, sc, sel, done2, xrow2, outf,
                                           attn_mem, stoprow, init_i, init_h, hv,
                                           w_ih, w_hh, b_ih, b_hh, gates, t);
    k_hc_b1<<<8, 256, 0, stream>>>(gates, init_c, cv0, cv1, hv, hop_wq, b1, t);
    k_hop<<<HOPBLK, 256, 0, stream>>>(hop_feat, b1, hop_v, qp, bmh, bZh);
    k_qn_b2<<<8, 1024, 0, stream>>>(qp, bmh, bZh, attn_wq, b2);
    k_attnT<<<NGRP, 256, 0, stream>>>(attn_featT, b2, attn_v, sel,
                                      gumbel + (size_t)t * NROWS, sc, bma, bZa, bkey);
  }
  k_tail<<<1, 256, 0, stream>>>(bma, bZa, bkey, sc, done2, outf);
}

// Round 8
// 2798.825 us; speedup vs baseline: 2.3550x; 2.3550x over previous
//
#include <hip/hip_runtime.h>
#include <math.h>

#define NITEMS 50000
#define NROWS 50001
#define NP 50048          // padded column count for transposed feat
#define DD 512
#define HH 512
#define TT 16
#define NEGV (-1e18f)
#define NGRP 782          // 50048/64 row-groups for attnT
#define HOPBLK 2048       // hop grid blocks (x4 waves = 8192 waves)

typedef unsigned long long ull;
typedef float f32x2 __attribute__((ext_vector_type(2)));

// ---- order-preserving float <-> uint key ----
__device__ __forceinline__ unsigned fkey(float f) {
  unsigned u = __float_as_uint(f);
  return (u & 0x80000000u) ? ~u : (u | 0x80000000u);
}

// fast tanh / exp via v_exp_f32 + v_rcp_f32
__device__ __forceinline__ float ftanh(float x) {
  float e = __builtin_amdgcn_exp2f(x * 2.885390081777927f);  // exp(2x)
  return 1.f - 2.f * __builtin_amdgcn_rcpf(e + 1.f);
}
__device__ __forceinline__ float fexp(float x) {
  return __builtin_amdgcn_exp2f(x * 1.4426950408889634f);
}

// packed fp32 FMA with in-register B-broadcast (lo / hi half)
__device__ __forceinline__ void pkfma_blo(f32x2& d, f32x2 a, f32x2 b) {
  asm("v_pk_fma_f32 %0, %1, %2, %0 op_sel:[0,0,0] op_sel_hi:[1,0,1]"
      : "+v"(d) : "v"(a), "v"(b));
}
__device__ __forceinline__ void pkfma_bhi(f32x2& d, f32x2 a, f32x2 b) {
  asm("v_pk_fma_f32 %0, %1, %2, %0 op_sel:[0,1,0] op_sel_hi:[1,1,1]"
      : "+v"(d) : "v"(a), "v"(b));
}

// ---------------- feat = mem @ W ; TR=1 stores transposed [n][m] (NP-padded) ----------------
template <int TR>
__launch_bounds__(256)
__global__ void k_feat_gemm(const float* __restrict__ A0, const float* __restrict__ stoprow,
                            const float* __restrict__ B, float* __restrict__ C) {
  __shared__ float As[8][128];
  __shared__ float Bs[8][128];
  const int tid = threadIdx.x;
  // ---- bijective XCD-chunk swizzle (1564 blocks; q=195, r=4) ----
  const int lid = blockIdx.y * 4 + blockIdx.x;
  const int xcd = lid & 7, pos = lid >> 3;
  const int orig = ((xcd < 4) ? xcd * 196 : 784 + (xcd - 4) * 195) + pos;
  const int m0 = (orig >> 2) * 128, n0 = (orig & 3) * 128;

  const int tx = tid & 15, ty = tid >> 4;
  const int ar = tid >> 1, ak = (tid & 1) * 4;
  const int bk = tid >> 5, bc = (tid & 31) * 4;
  const int arow = m0 + ar;
  const float* Arow = (arow < NITEMS) ? (A0 + (size_t)arow * DD) : stoprow;
  const bool avalid = (arow < NROWS);
  f32x2 acc2[4][8];
#pragma unroll
  for (int i = 0; i < 4; ++i)
#pragma unroll
    for (int j = 0; j < 8; ++j) acc2[i][j] = (f32x2){0.f, 0.f};

  for (int kt = 0; kt < DD; kt += 8) {
    float4 av = avalid ? *(const float4*)(Arow + kt + ak) : make_float4(0.f, 0.f, 0.f, 0.f);
    As[ak + 0][ar] = av.x;
    As[ak + 1][ar] = av.y;
    As[ak + 2][ar] = av.z;
    As[ak + 3][ar] = av.w;
    *(float4*)&Bs[bk][bc] = *(const float4*)(B + (size_t)(kt + bk) * HH + n0 + bc);
    __syncthreads();
#pragma unroll
    for (int k = 0; k < 8; ++k) {
      const f32x2* ap = (const f32x2*)&As[k][ty * 8];
      const f32x2* bp0 = (const f32x2*)&Bs[k][tx * 4];
      const f32x2* bp1 = (const f32x2*)&Bs[k][64 + tx * 4];
      f32x2 a2[4] = {ap[0], ap[1], ap[2], ap[3]};
      f32x2 b2[4] = {bp0[0], bp0[1], bp1[0], bp1[1]};
#pragma unroll
      for (int ii = 0; ii < 4; ++ii) {
#pragma unroll
        for (int jj = 0; jj < 4; ++jj) {
          pkfma_blo(acc2[ii][2 * jj], a2[ii], b2[jj]);
          pkfma_bhi(acc2[ii][2 * jj + 1], a2[ii], b2[jj]);
        }
      }
    }
    __syncthreads();
  }
  if (TR) {
#pragma unroll
    for (int c = 0; c < 8; ++c) {
      const int n = (c < 4) ? (n0 + tx * 4 + c) : (n0 + 64 + tx * 4 + (c - 4));
      float* cp = C + (size_t)n * NP + m0 + ty * 8;
      *(float4*)cp = make_float4(acc2[0][c].x, acc2[0][c].y, acc2[1][c].x, acc2[1][c].y);
      *(float4*)(cp + 4) = make_float4(acc2[2][c].x, acc2[2][c].y, acc2[3][c].x, acc2[3][c].y);
    }
  } else {
#pragma unroll
    for (int ii = 0; ii < 4; ++ii) {
#pragma unroll
      for (int half = 0; half < 2; ++half) {
        const int row = m0 + ty * 8 + 2 * ii + half;
        if (row < NROWS) {
          float* crow = C + (size_t)row * HH + n0;
          if (half == 0) {
            *(float4*)(crow + tx * 4) =
                make_float4(acc2[ii][0].x, acc2[ii][1].x, acc2[ii][2].x, acc2[ii][3].x);
            *(float4*)(crow + 64 + tx * 4) =
                make_float4(acc2[ii][4].x, acc2[ii][5].x, acc2[ii][6].x, acc2[ii][7].x);
          } else {
            *(float4*)(crow + tx * 4) =
                make_float4(acc2[ii][0].y, acc2[ii][1].y, acc2[ii][2].y, acc2[ii][3].y);
            *(float4*)(crow + 64 + tx * 4) =
                make_float4(acc2[ii][4].y, acc2[ii][5].y, acc2[ii][6].y, acc2[ii][7].y);
          }
        }
      }
    }
  }
}

// ---------------- zero sel ----------------
__global__ void k_zero(int* __restrict__ sel) {
  int i = blockIdx.x * 256 + threadIdx.x;
  if (i < NROWS) sel[i] = 0;
}

// ---------------- finalize prev step (redundant in all blocks) + LSTM gates ----------------
// No-max log-softmax: logp = sc[out] - log(sum exp(s))  (scores bounded, exp safe in fp32)
__launch_bounds__(256)
__global__ void k_final_gates(const float* __restrict__ bZa, const ull* __restrict__ bkey,
                              const float* __restrict__ sc,
                              int* __restrict__ sel, int* __restrict__ done2,
                              int* __restrict__ xrow2, float* __restrict__ outf,
                              const float* __restrict__ attn_mem, const float* __restrict__ stoprow,
                              const float* __restrict__ init_i, const float* __restrict__ init_h,
                              const float* __restrict__ hv,
                              const float* __restrict__ w_ih, const float* __restrict__ w_hh,
                              const float* __restrict__ b_ih, const float* __restrict__ b_hh,
                              float* __restrict__ gates, int t) {
  __shared__ float redz[256];
  __shared__ ull redk[256];
  const int tid = threadIdx.x, blk = blockIdx.x;
  const int w = tid >> 6, lane = tid & 63;
  int xrow = -1;
  if (t > 0) {
    float Zl = 0.f;
    ull Kl = 0;
    for (int i = tid; i < NGRP; i += 256) {
      Zl += bZa[i];
      ull k = bkey[i];
      if (k > Kl) Kl = k;
    }
    redz[tid] = Zl;
    redk[tid] = Kl;
    __syncthreads();
    for (int s2 = 128; s2 > 0; s2 >>= 1) {
      if (tid < s2) {
        redz[tid] += redz[tid + s2];
        if (redk[tid + s2] > redk[tid]) redk[tid] = redk[tid + s2];
      }
      __syncthreads();
    }
    const float Z = redz[0];
    const ull K = redk[0];
    const int out = NITEMS - (int)(unsigned)(K & 0xffffffffull);
    const int d_in = (t == 1) ? 0 : done2[(t - 1) & 1];
    const int xprev = (t == 1) ? -1 : xrow2[(t - 1) & 1];
    const int nd = d_in | (out == NITEMS);
    xrow = nd ? xprev : out;
    if (blk == 0 && tid == 0) {
      outf[t - 1] = (float)(d_in ? NITEMS : out);
      outf[TT + t - 1] = d_in ? 0.f : (sc[out] - logf(Z));
      if (!d_in) sel[out] = 1;
      done2[t & 1] = nd;
      xrow2[t & 1] = xrow;
    }
  }
  // LSTM gate row r = blk*4 + w  (512 blocks x 4 waves = 2048 rows)
  const int r = blk * 4 + w;
  const float* xp = (xrow < 0) ? init_i
                               : ((xrow == NITEMS) ? stoprow : attn_mem + (size_t)xrow * DD);
  const float* hp = (t == 0) ? init_h : hv;
  const float4* x4 = (const float4*)xp;
  const float4* h4 = (const float4*)hp;
  const float4* wi = (const float4*)(w_ih + (size_t)r * DD);
  const float4* wh = (const float4*)(w_hh + (size_t)r * DD);
  float s = 0.f;
  float4 a, ww;
  a = x4[lane * 2];     ww = wi[lane * 2];     s += a.x * ww.x + a.y * ww.y + a.z * ww.z + a.w * ww.w;
  a = x4[lane * 2 + 1]; ww = wi[lane * 2 + 1]; s += a.x * ww.x + a.y * ww.y + a.z * ww.z + a.w * ww.w;
  a = h4[lane * 2];     ww = wh[lane * 2];     s += a.x * ww.x + a.y * ww.y + a.z * ww.z + a.w * ww.w;
  a = h4[lane * 2 + 1]; ww = wh[lane * 2 + 1]; s += a.x * ww.x + a.y * ww.y + a.z * ww.z + a.w * ww.w;
#pragma unroll
  for (int off = 32; off > 0; off >>= 1) s += __shfl_xor(s, off);
  if (lane == 0) gates[r] = s + b_ih[r] + b_hh[r];
}

// ---------------- h,c update (redundant x8) + b1 = h @ hop_wq ----------------
__launch_bounds__(256)
__global__ void k_hc_b1(const float* __restrict__ gates, const float* __restrict__ init_c,
                        float* __restrict__ cv0, float* __restrict__ cv1, float* __restrict__ hv,
                        const float* __restrict__ hop_wq, float* __restrict__ b1, int t) {
  __shared__ float h[512];
  __shared__ float red[256];
  const int tid = threadIdx.x, blk = blockIdx.x;
  const float* csrc = (t == 0) ? init_c : ((t & 1) ? cv1 : cv0);
  float* cdst = (t & 1) ? cv0 : cv1;
  for (int i = tid; i < 512; i += 256) {
    float gi = gates[i], gf = gates[512 + i], gg = gates[1024 + i], go = gates[1536 + i];
    float si = 1.f / (1.f + expf(-gi));
    float sf = 1.f / (1.f + expf(-gf));
    float so = 1.f / (1.f + expf(-go));
    float cn = sf * csrc[i] + si * tanhf(gg);
    float hval = so * tanhf(cn);
    h[i] = hval;
    if (blk == 0) { cdst[i] = cn; hv[i] = hval; }
  }
  __syncthreads();
  const int cc = tid & 63, q = tid >> 6;
  const int j = blk * 64 + cc;
  float pb = 0.f;
  for (int i = q * 128; i < q * 128 + 128; ++i) pb = fmaf(h[i], hop_wq[(size_t)i * HH + j], pb);
  red[tid] = pb;
  __syncthreads();
  if (tid < 64) b1[blk * 64 + tid] = red[tid] + red[tid + 64] + red[tid + 128] + red[tid + 192];
}

// ---------------- hop: fused score + softmax-weighted sum, NO max-shift (scores bounded) ----------------
__launch_bounds__(256)
__global__ void k_hop(const float* __restrict__ feat, const float* __restrict__ bvec,
                      const float* __restrict__ v, float* __restrict__ qp,
                      float* __restrict__ bZh) {
  __shared__ float sz[4];
  __shared__ float qbuf[4][512];
  const int tid = threadIdx.x, blk = blockIdx.x;
  const int w = tid >> 6, lane = tid & 63;
  const int wv = blk * 4 + w;
  float bv[8], vv[8], qa[8];
#pragma unroll
  for (int j = 0; j < 8; ++j) { bv[j] = bvec[lane * 8 + j]; vv[j] = v[lane * 8 + j]; qa[j] = 0.f; }
  float Z = 0.f;
  for (int m = wv; m < NROWS; m += 4 * HOPBLK) {
    const float4* fp = (const float4*)(feat + (size_t)m * HH);
    float4 A = fp[lane * 2], B = fp[lane * 2 + 1];
    float f[8] = {A.x, A.y, A.z, A.w, B.x, B.y, B.z, B.w};
    float s = 0.f;
#pragma unroll
    for (int j = 0; j < 8; ++j) s += ftanh(f[j] + bv[j]) * vv[j];
#pragma unroll
    for (int off = 32; off > 0; off >>= 1) s += __shfl_xor(s, off);
    const float e = fexp(s);
    Z += e;
#pragma unroll
    for (int j = 0; j < 8; ++j) qa[j] = fmaf(e, f[j], qa[j]);
  }
  if (lane == 0) sz[w] = Z;
#pragma unroll
  for (int j = 0; j < 8; ++j) qbuf[w][lane * 8 + j] = qa[j];
  __syncthreads();
  float a0 = 0.f, a1 = 0.f;
#pragma unroll
  for (int w2 = 0; w2 < 4; ++w2) { a0 += qbuf[w2][tid]; a1 += qbuf[w2][tid + 256]; }
  qp[(size_t)blk * 512 + tid] = a0;
  qp[(size_t)blk * 512 + tid + 256] = a1;
  if (tid == 0) bZh[blk] = sz[0] + sz[1] + sz[2] + sz[3];
}

// ---------------- combine 2048 hop partials -> qn (straight sums) ----------------
__launch_bounds__(1024)
__global__ void k_qn(const float* __restrict__ qp, const float* __restrict__ bZh,
                     float* __restrict__ qn) {
  __shared__ float red[1024];
  const int tid = threadIdx.x;
  red[tid] = bZh[tid] + bZh[tid + 1024];
  __syncthreads();
  for (int s2 = 512; s2 > 0; s2 >>= 1) {
    if (tid < s2) red[tid] += red[tid + s2];
    __syncthreads();
  }
  const float Z = red[0];
  __syncthreads();
  const int cc = tid & 31, q = tid >> 5;  // q: 0..31
  const int col = blockIdx.x * 32 + cc;
  float acc = 0.f;
  for (int p = q * 64; p < q * 64 + 64; ++p) acc += qp[(size_t)p * 512 + col];
  red[tid] = acc;
  __syncthreads();
  if (tid < 32) {
    float a = 0.f;
#pragma unroll
    for (int g = 0; g < 32; ++g) a += red[tid + 32 * g];
    qn[blockIdx.x * 32 + tid] = a / Z;
  }
}

// ---------------- b2[j] = sum_i qn[i] * W[i][j] ----------------
__launch_bounds__(256)
__global__ void k_gemv(const float* __restrict__ q, const float* __restrict__ W,
                       float* __restrict__ out) {
  __shared__ float lds[256];
  const int tid = threadIdx.x;
  const int cc = tid & 63, rs = tid >> 6;
  const int j = blockIdx.x * 64 + cc;
  float p = 0.f;
  for (int i = rs * 128; i < rs * 128 + 128; ++i) p += q[i] * W[(size_t)i * HH + j];
  lds[tid] = p;
  __syncthreads();
  if (tid < 64) out[blockIdx.x * 64 + tid] = lds[tid] + lds[tid + 64] + lds[tid + 128] + lds[tid + 192];
}

// ---------------- attn: transposed sweep; per-group Z-sum + gumbel key (no max tracking) ----------------
__launch_bounds__(256)
__global__ void k_attnT(const float* __restrict__ featT, const float* __restrict__ b2,
                        const float* __restrict__ av, const int* __restrict__ sel,
                        const float* __restrict__ gum, float* __restrict__ sc,
                        float* __restrict__ bZa, ull* __restrict__ bkey) {
  __shared__ float spart[4][64];
  const int tid = threadIdx.x, g = blockIdx.x;
  const int w = tid >> 6, lane = tid & 63;
  const int m = g * 64 + lane;   // < NP always (padded)
  const int h0 = w * 128;
  const float* fp = featT + (size_t)h0 * NP + m;
  float acc = 0.f;
#pragma unroll 8
  for (int hh = 0; hh < 128; ++hh) {
    float f = *fp;
    fp += NP;
    acc += ftanh(f + b2[h0 + hh]) * av[h0 + hh];
  }
  spart[w][lane] = acc;
  __syncthreads();
  if (w == 0) {
    float s = spart[0][lane] + spart[1][lane] + spart[2][lane] + spart[3][lane];
    const bool valid = (m < NROWS);
    float Z;
    ull key;
    if (valid) {
      float se = sel[m] ? NEGV : s;
      sc[m] = se;
      key = ((ull)fkey(se + gum[m]) << 32) | (unsigned)(NITEMS - m);
      Z = fexp(se);  // exp(-1e18) underflows to 0 for masked
    } else {
      key = 0;
      Z = 0.f;
    }
#pragma unroll
    for (int off = 32; off > 0; off >>= 1) {
      Z += __shfl_xor(Z, off);
      ull Ko = __shfl_xor(key, off);
      if (Ko > key) key = Ko;
    }
    if (lane == 0) { bZa[g] = Z; bkey[g] = key; }
  }
}

// ---------------- final outputs for step 15 ----------------
__launch_bounds__(256)
__global__ void k_tail(const float* __restrict__ bZa, const ull* __restrict__ bkey,
                       const float* __restrict__ sc, const int* __restrict__ done2,
                       float* __restrict__ outf) {
  __shared__ float redz[256];
  __shared__ ull redk[256];
  const int tid = threadIdx.x;
  float Zl = 0.f;
  ull Kl = 0;
  for (int i = tid; i < NGRP; i += 256) {
    Zl += bZa[i];
    ull k = bkey[i];
    if (k > Kl) Kl = k;
  }
  redz[tid] = Zl;
  redk[tid] = Kl;
  __syncthreads();
  for (int s2 = 128; s2 > 0; s2 >>= 1) {
    if (tid < s2) {
      redz[tid] += redz[tid + s2];
      if (redk[tid + s2] > redk[tid]) redk[tid] = redk[tid + s2];
    }
    __syncthreads();
  }
  if (tid == 0) {
    const float Z = redz[0];
    const ull K = redk[0];
    const int out = NITEMS - (int)(unsigned)(K & 0xffffffffull);
    const int d_in = done2[(TT - 1) & 1];
    outf[TT - 1] = (float)(d_in ? NITEMS : out);
    outf[2 * TT - 1] = d_in ? 0.f : (sc[out] - logf(Z));
  }
}

// ======================================================================
extern "C" void kernel_launch(void* const* d_in, const int* in_sizes, int n_in,
                              void* d_out, int out_size, void* d_ws, size_t ws_size,
                              hipStream_t stream) {
  const float* attn_mem = (const float*)d_in[0];
  const float* stoprow  = (const float*)d_in[1];
  const float* init_h   = (const float*)d_in[2];
  const float* init_c   = (const float*)d_in[3];
  const float* init_i   = (const float*)d_in[4];
  const float* attn_wm  = (const float*)d_in[5];
  const float* attn_wq  = (const float*)d_in[6];
  const float* attn_v   = (const float*)d_in[7];
  const float* hop_wm   = (const float*)d_in[8];
  const float* hop_wq   = (const float*)d_in[9];
  const float* hop_v    = (const float*)d_in[10];
  const float* w_ih     = (const float*)d_in[11];
  const float* w_hh     = (const float*)d_in[12];
  const float* b_ih     = (const float*)d_in[13];
  const float* b_hh     = (const float*)d_in[14];
  const float* gumbel   = (const float*)d_in[15];

  float* ws = (float*)d_ws;
  size_t fo = 0;
  float* hop_feat   = ws + fo; fo += (size_t)NROWS * HH;   // normal layout
  float* attn_featT = ws + fo; fo += (size_t)HH * NP;      // transposed, padded
  float* sc  = ws + fo; fo += 50048;
  int* sel   = (int*)(ws + fo); fo += 50048;
  float* qp  = ws + fo; fo += (size_t)HOPBLK * 512;
  float* bZh = ws + fo; fo += HOPBLK;
  float* bZa = ws + fo; fo += 1024;
  ull* bkey  = (ull*)(ws + fo); fo += 2048;
  float* gates = ws + fo; fo += 4 * HH;
  float* hv  = ws + fo; fo += HH;
  float* cv0 = ws + fo; fo += HH;
  float* cv1 = ws + fo; fo += HH;
  float* b1  = ws + fo; fo += HH;
  float* b2  = ws + fo; fo += HH;
  float* qn  = ws + fo; fo += HH;
  int* done2 = (int*)(ws + fo); fo += 2;
  int* xrow2 = (int*)(ws + fo); fo += 2;
  if (fo * sizeof(float) > ws_size) return;

  float* outf = (float*)d_out;

  k_zero<<<196, 256, 0, stream>>>(sel);
  dim3 ggrid(4, (NP + 127) / 128);  // 391 m-tiles x 4 n-tiles = 1564 blocks
  k_feat_gemm<1><<<ggrid, 256, 0, stream>>>(attn_mem, stoprow, attn_wm, attn_featT);
  k_feat_gemm<0><<<ggrid, 256, 0, stream>>>(attn_mem, stoprow, hop_wm, hop_feat);

  for (int t = 0; t < TT; ++t) {
    k_final_gates<<<512, 256, 0, stream>>>(bZa, bkey, sc, sel, done2, xrow2, outf,
                                           attn_mem, stoprow, init_i, init_h, hv,
                                           w_ih, w_hh, b_ih, b_hh, gates, t);
    k_hc_b1<<<8, 256, 0, stream>>>(gates, init_c, cv0, cv1, hv, hop_wq, b1, t);
    k_hop<<<HOPBLK, 256, 0, stream>>>(hop_feat, b1, hop_v, qp, bZh);
    k_qn<<<16, 1024, 0, stream>>>(qp, bZh, qn);
    k_gemv<<<8, 256, 0, stream>>>(qn, attn_wq, b2);
    k_attnT<<<NGRP, 256, 0, stream>>>(attn_featT, b2, attn_v, sel,
                                      gumbel + (size_t)t * NROWS, sc, bZa, bkey);
  }
  k_tail<<<1, 256, 0, stream>>>(bZa, bkey, sc, done2, outf);
}

// Round 9
// 2559.114 us; speedup vs baseline: 2.5755x; 1.0937x over previous
//
#include <hip/hip_runtime.h>
#include <math.h>

#define NITEMS 50000
#define NROWS 50001
#define NP 50048          // padded column count for transposed feat
#define DD 512
#define HH 512
#define TT 16
#define NEGV (-1e18f)
#define NGRP 782          // 50048/64 groups of 64 rows (attn partials)
#define HOPBLK 2048       // hop grid blocks (x4 waves = 8192 waves)

typedef unsigned long long ull;
typedef unsigned short ushort;
typedef float f32x2 __attribute__((ext_vector_type(2)));

// ---- order-preserving float <-> uint key ----
__device__ __forceinline__ unsigned fkey(float f) {
  unsigned u = __float_as_uint(f);
  return (u & 0x80000000u) ? ~u : (u | 0x80000000u);
}

// fast tanh / exp via v_exp_f32 + v_rcp_f32
__device__ __forceinline__ float ftanh(float x) {
  float e = __builtin_amdgcn_exp2f(x * 2.885390081777927f);  // exp(2x)
  return 1.f - 2.f * __builtin_amdgcn_rcpf(e + 1.f);
}
__device__ __forceinline__ float fexp(float x) {
  return __builtin_amdgcn_exp2f(x * 1.4426950408889634f);
}

// ---- bf16 pack/unpack (RNE) ----
__device__ __forceinline__ unsigned pack_bf16(float a, float b) {
  unsigned ua = __float_as_uint(a), ub = __float_as_uint(b);
  ua = (ua + 0x7fffu + ((ua >> 16) & 1u)) >> 16;
  ub = (ub + 0x7fffu + ((ub >> 16) & 1u)) >> 16;
  return ua | (ub << 16);
}
__device__ __forceinline__ float bflo(unsigned u) { return __uint_as_float(u << 16); }
__device__ __forceinline__ float bfhi(unsigned u) { return __uint_as_float(u & 0xffff0000u); }

// packed fp32 FMA with in-register B-broadcast (lo / hi half)
__device__ __forceinline__ void pkfma_blo(f32x2& d, f32x2 a, f32x2 b) {
  asm("v_pk_fma_f32 %0, %1, %2, %0 op_sel:[0,0,0] op_sel_hi:[1,0,1]"
      : "+v"(d) : "v"(a), "v"(b));
}
__device__ __forceinline__ void pkfma_bhi(f32x2& d, f32x2 a, f32x2 b) {
  asm("v_pk_fma_f32 %0, %1, %2, %0 op_sel:[0,1,0] op_sel_hi:[1,1,1]"
      : "+v"(d) : "v"(a), "v"(b));
}

// ---------------- feat = mem @ W -> bf16 ; TR=1 stores transposed [n][m] (NP-padded) ----------------
template <int TR>
__launch_bounds__(256)
__global__ void k_feat_gemm(const float* __restrict__ A0, const float* __restrict__ stoprow,
                            const float* __restrict__ B, ushort* __restrict__ C) {
  __shared__ float As[8][128];
  __shared__ float Bs[8][128];
  const int tid = threadIdx.x;
  // ---- bijective XCD-chunk swizzle (1564 blocks; q=195, r=4) ----
  const int lid = blockIdx.y * 4 + blockIdx.x;
  const int xcd = lid & 7, pos = lid >> 3;
  const int orig = ((xcd < 4) ? xcd * 196 : 784 + (xcd - 4) * 195) + pos;
  const int m0 = (orig >> 2) * 128, n0 = (orig & 3) * 128;

  const int tx = tid & 15, ty = tid >> 4;
  const int ar = tid >> 1, ak = (tid & 1) * 4;
  const int bk = tid >> 5, bc = (tid & 31) * 4;
  const int arow = m0 + ar;
  const float* Arow = (arow < NITEMS) ? (A0 + (size_t)arow * DD) : stoprow;
  const bool avalid = (arow < NROWS);
  f32x2 acc2[4][8];
#pragma unroll
  for (int i = 0; i < 4; ++i)
#pragma unroll
    for (int j = 0; j < 8; ++j) acc2[i][j] = (f32x2){0.f, 0.f};

  for (int kt = 0; kt < DD; kt += 8) {
    float4 av = avalid ? *(const float4*)(Arow + kt + ak) : make_float4(0.f, 0.f, 0.f, 0.f);
    As[ak + 0][ar] = av.x;
    As[ak + 1][ar] = av.y;
    As[ak + 2][ar] = av.z;
    As[ak + 3][ar] = av.w;
    *(float4*)&Bs[bk][bc] = *(const float4*)(B + (size_t)(kt + bk) * HH + n0 + bc);
    __syncthreads();
#pragma unroll
    for (int k = 0; k < 8; ++k) {
      const f32x2* ap = (const f32x2*)&As[k][ty * 8];
      const f32x2* bp0 = (const f32x2*)&Bs[k][tx * 4];
      const f32x2* bp1 = (const f32x2*)&Bs[k][64 + tx * 4];
      f32x2 a2[4] = {ap[0], ap[1], ap[2], ap[3]};
      f32x2 b2[4] = {bp0[0], bp0[1], bp1[0], bp1[1]};
#pragma unroll
      for (int ii = 0; ii < 4; ++ii) {
#pragma unroll
        for (int jj = 0; jj < 4; ++jj) {
          pkfma_blo(acc2[ii][2 * jj], a2[ii], b2[jj]);
          pkfma_bhi(acc2[ii][2 * jj + 1], a2[ii], b2[jj]);
        }
      }
    }
    __syncthreads();
  }
  if (TR) {
    // featT[n][m0+ty*8 .. +7] -> 8 bf16 = one uint4 store
#pragma unroll
    for (int c = 0; c < 8; ++c) {
      const int n = (c < 4) ? (n0 + tx * 4 + c) : (n0 + 64 + tx * 4 + (c - 4));
      ushort* cp = C + (size_t)n * NP + m0 + ty * 8;
      *(uint4*)cp = make_uint4(pack_bf16(acc2[0][c].x, acc2[0][c].y),
                               pack_bf16(acc2[1][c].x, acc2[1][c].y),
                               pack_bf16(acc2[2][c].x, acc2[2][c].y),
                               pack_bf16(acc2[3][c].x, acc2[3][c].y));
    }
  } else {
#pragma unroll
    for (int ii = 0; ii < 4; ++ii) {
#pragma unroll
      for (int half = 0; half < 2; ++half) {
        const int row = m0 + ty * 8 + 2 * ii + half;
        if (row < NROWS) {
          ushort* crow = C + (size_t)row * HH + n0;
          if (half == 0) {
            *(uint2*)(crow + tx * 4) =
                make_uint2(pack_bf16(acc2[ii][0].x, acc2[ii][1].x),
                           pack_bf16(acc2[ii][2].x, acc2[ii][3].x));
            *(uint2*)(crow + 64 + tx * 4) =
                make_uint2(pack_bf16(acc2[ii][4].x, acc2[ii][5].x),
                           pack_bf16(acc2[ii][6].x, acc2[ii][7].x));
          } else {
            *(uint2*)(crow + tx * 4) =
                make_uint2(pack_bf16(acc2[ii][0].y, acc2[ii][1].y),
                           pack_bf16(acc2[ii][2].y, acc2[ii][3].y));
            *(uint2*)(crow + 64 + tx * 4) =
                make_uint2(pack_bf16(acc2[ii][4].y, acc2[ii][5].y),
                           pack_bf16(acc2[ii][6].y, acc2[ii][7].y));
          }
        }
      }
    }
  }
}

// ---------------- zero sel ----------------
__global__ void k_zero(int* __restrict__ sel) {
  int i = blockIdx.x * 256 + threadIdx.x;
  if (i < NROWS) sel[i] = 0;
}

// ---------------- finalize prev step (redundant in all blocks) + LSTM gates ----------------
__launch_bounds__(256)
__global__ void k_final_gates(const float* __restrict__ bZa, const ull* __restrict__ bkey,
                              const float* __restrict__ sc,
                              int* __restrict__ sel, int* __restrict__ done2,
                              int* __restrict__ xrow2, float* __restrict__ outf,
                              const float* __restrict__ attn_mem, const float* __restrict__ stoprow,
                              const float* __restrict__ init_i, const float* __restrict__ init_h,
                              const float* __restrict__ hv,
                              const float* __restrict__ w_ih, const float* __restrict__ w_hh,
                              const float* __restrict__ b_ih, const float* __restrict__ b_hh,
                              float* __restrict__ gates, int t) {
  __shared__ float redz[256];
  __shared__ ull redk[256];
  const int tid = threadIdx.x, blk = blockIdx.x;
  const int w = tid >> 6, lane = tid & 63;
  int xrow = -1;
  if (t > 0) {
    float Zl = 0.f;
    ull Kl = 0;
    for (int i = tid; i < NGRP; i += 256) {
      Zl += bZa[i];
      ull k = bkey[i];
      if (k > Kl) Kl = k;
    }
    redz[tid] = Zl;
    redk[tid] = Kl;
    __syncthreads();
    for (int s2 = 128; s2 > 0; s2 >>= 1) {
      if (tid < s2) {
        redz[tid] += redz[tid + s2];
        if (redk[tid + s2] > redk[tid]) redk[tid] = redk[tid + s2];
      }
      __syncthreads();
    }
    const float Z = redz[0];
    const ull K = redk[0];
    const int out = NITEMS - (int)(unsigned)(K & 0xffffffffull);
    const int d_in = (t == 1) ? 0 : done2[(t - 1) & 1];
    const int xprev = (t == 1) ? -1 : xrow2[(t - 1) & 1];
    const int nd = d_in | (out == NITEMS);
    xrow = nd ? xprev : out;
    if (blk == 0 && tid == 0) {
      outf[t - 1] = (float)(d_in ? NITEMS : out);
      outf[TT + t - 1] = d_in ? 0.f : (sc[out] - logf(Z));
      if (!d_in) sel[out] = 1;
      done2[t & 1] = nd;
      xrow2[t & 1] = xrow;
    }
  }
  // LSTM gate row r = blk*4 + w  (512 blocks x 4 waves = 2048 rows)
  const int r = blk * 4 + w;
  const float* xp = (xrow < 0) ? init_i
                               : ((xrow == NITEMS) ? stoprow : attn_mem + (size_t)xrow * DD);
  const float* hp = (t == 0) ? init_h : hv;
  const float4* x4 = (const float4*)xp;
  const float4* h4 = (const float4*)hp;
  const float4* wi = (const float4*)(w_ih + (size_t)r * DD);
  const float4* wh = (const float4*)(w_hh + (size_t)r * DD);
  float s = 0.f;
  float4 a, ww;
  a = x4[lane * 2];     ww = wi[lane * 2];     s += a.x * ww.x + a.y * ww.y + a.z * ww.z + a.w * ww.w;
  a = x4[lane * 2 + 1]; ww = wi[lane * 2 + 1]; s += a.x * ww.x + a.y * ww.y + a.z * ww.z + a.w * ww.w;
  a = h4[lane * 2];     ww = wh[lane * 2];     s += a.x * ww.x + a.y * ww.y + a.z * ww.z + a.w * ww.w;
  a = h4[lane * 2 + 1]; ww = wh[lane * 2 + 1]; s += a.x * ww.x + a.y * ww.y + a.z * ww.z + a.w * ww.w;
#pragma unroll
  for (int off = 32; off > 0; off >>= 1) s += __shfl_xor(s, off);
  if (lane == 0) gates[r] = s + b_ih[r] + b_hh[r];
}

// ---------------- h,c update (redundant x8) + b1 = h @ hop_wq ----------------
__launch_bounds__(256)
__global__ void k_hc_b1(const float* __restrict__ gates, const float* __restrict__ init_c,
                        float* __restrict__ cv0, float* __restrict__ cv1, float* __restrict__ hv,
                        const float* __restrict__ hop_wq, float* __restrict__ b1, int t) {
  __shared__ float h[512];
  __shared__ float red[256];
  const int tid = threadIdx.x, blk = blockIdx.x;
  const float* csrc = (t == 0) ? init_c : ((t & 1) ? cv1 : cv0);
  float* cdst = (t & 1) ? cv0 : cv1;
  for (int i = tid; i < 512; i += 256) {
    float gi = gates[i], gf = gates[512 + i], gg = gates[1024 + i], go = gates[1536 + i];
    float si = 1.f / (1.f + expf(-gi));
    float sf = 1.f / (1.f + expf(-gf));
    float so = 1.f / (1.f + expf(-go));
    float cn = sf * csrc[i] + si * tanhf(gg);
    float hval = so * tanhf(cn);
    h[i] = hval;
    if (blk == 0) { cdst[i] = cn; hv[i] = hval; }
  }
  __syncthreads();
  const int cc = tid & 63, q = tid >> 6;
  const int j = blk * 64 + cc;
  float pb = 0.f;
  for (int i = q * 128; i < q * 128 + 128; ++i) pb = fmaf(h[i], hop_wq[(size_t)i * HH + j], pb);
  red[tid] = pb;
  __syncthreads();
  if (tid < 64) b1[blk * 64 + tid] = red[tid] + red[tid + 64] + red[tid + 128] + red[tid + 192];
}

// ---------------- hop: fused score + softmax-weighted sum over bf16 feat ----------------
__launch_bounds__(256)
__global__ void k_hop(const ushort* __restrict__ feat, const float* __restrict__ bvec,
                      const float* __restrict__ v, float* __restrict__ qp,
                      float* __restrict__ bZh) {
  __shared__ float sz[4];
  __shared__ float qbuf[4][512];
  const int tid = threadIdx.x, blk = blockIdx.x;
  const int w = tid >> 6, lane = tid & 63;
  const int wv = blk * 4 + w;
  float bv[8], vv[8], qa[8];
#pragma unroll
  for (int j = 0; j < 8; ++j) { bv[j] = bvec[lane * 8 + j]; vv[j] = v[lane * 8 + j]; qa[j] = 0.f; }
  float Z = 0.f;
  for (int m = wv; m < NROWS; m += 4 * HOPBLK) {
    const uint4* fp = (const uint4*)(feat + (size_t)m * HH);
    uint4 U = fp[lane];
    float f[8] = {bflo(U.x), bfhi(U.x), bflo(U.y), bfhi(U.y),
                  bflo(U.z), bfhi(U.z), bflo(U.w), bfhi(U.w)};
    float s = 0.f;
#pragma unroll
    for (int j = 0; j < 8; ++j) s += ftanh(f[j] + bv[j]) * vv[j];
#pragma unroll
    for (int off = 32; off > 0; off >>= 1) s += __shfl_xor(s, off);
    const float e = fexp(s);
    Z += e;
#pragma unroll
    for (int j = 0; j < 8; ++j) qa[j] = fmaf(e, f[j], qa[j]);
  }
  if (lane == 0) sz[w] = Z;
#pragma unroll
  for (int j = 0; j < 8; ++j) qbuf[w][lane * 8 + j] = qa[j];
  __syncthreads();
  float a0 = 0.f, a1 = 0.f;
#pragma unroll
  for (int w2 = 0; w2 < 4; ++w2) { a0 += qbuf[w2][tid]; a1 += qbuf[w2][tid + 256]; }
  qp[(size_t)blk * 512 + tid] = a0;
  qp[(size_t)blk * 512 + tid + 256] = a1;
  if (tid == 0) bZh[blk] = sz[0] + sz[1] + sz[2] + sz[3];
}

// ---------------- combine 2048 hop partials -> qn (straight sums) ----------------
__launch_bounds__(1024)
__global__ void k_qn(const float* __restrict__ qp, const float* __restrict__ bZh,
                     float* __restrict__ qn) {
  __shared__ float red[1024];
  const int tid = threadIdx.x;
  red[tid] = bZh[tid] + bZh[tid + 1024];
  __syncthreads();
  for (int s2 = 512; s2 > 0; s2 >>= 1) {
    if (tid < s2) red[tid] += red[tid + s2];
    __syncthreads();
  }
  const float Z = red[0];
  __syncthreads();
  const int cc = tid & 31, q = tid >> 5;
  const int col = blockIdx.x * 32 + cc;
  float acc = 0.f;
  for (int p = q * 64; p < q * 64 + 64; ++p) acc += qp[(size_t)p * 512 + col];
  red[tid] = acc;
  __syncthreads();
  if (tid < 32) {
    float a = 0.f;
#pragma unroll
    for (int g = 0; g < 32; ++g) a += red[tid + 32 * g];
    qn[blockIdx.x * 32 + tid] = a / Z;
  }
}

// ---------------- b2[j] = sum_i qn[i] * W[i][j] ----------------
__launch_bounds__(256)
__global__ void k_gemv(const float* __restrict__ q, const float* __restrict__ W,
                       float* __restrict__ out) {
  __shared__ float lds[256];
  const int tid = threadIdx.x;
  const int cc = tid & 63, rs = tid >> 6;
  const int j = blockIdx.x * 64 + cc;
  float p = 0.f;
  for (int i = rs * 128; i < rs * 128 + 128; ++i) p += q[i] * W[(size_t)i * HH + j];
  lds[tid] = p;
  __syncthreads();
  if (tid < 64) out[blockIdx.x * 64 + tid] = lds[tid] + lds[tid + 64] + lds[tid + 128] + lds[tid + 192];
}

// ---------------- attn: bf16 transposed sweep — 391 blocks x 8 waves, 128 rows/block ----------------
__launch_bounds__(512)
__global__ void k_attnT(const ushort* __restrict__ featT, const float* __restrict__ b2,
                        const float* __restrict__ av, const int* __restrict__ sel,
                        const float* __restrict__ gum, float* __restrict__ sc,
                        float* __restrict__ bZa, ull* __restrict__ bkey) {
  __shared__ float spart[8][128];
  const int tid = threadIdx.x, g = blockIdx.x;
  const int w = tid >> 6, lane = tid & 63;
  const int mb = g * 128 + lane * 2;   // this lane's two rows (< NP, padded)
  const int h0 = w * 64;
  const ushort* fp = featT + (size_t)h0 * NP + mb;
  float acc0 = 0.f, acc1 = 0.f;
#pragma unroll 8
  for (int hh = 0; hh < 64; ++hh) {
    const unsigned u = *(const unsigned*)fp;  // 2 bf16: rows mb (lo), mb+1 (hi)
    fp += NP;
    const float bb = b2[h0 + hh], vv = av[h0 + hh];
    acc0 += ftanh(bflo(u) + bb) * vv;
    acc1 += ftanh(bfhi(u) + bb) * vv;
  }
  spart[w][lane * 2] = acc0;
  spart[w][lane * 2 + 1] = acc1;
  __syncthreads();
  if (w < 2) {
    const int idx = w * 64 + lane;      // 0..127 within block
    const int m = g * 128 + idx;
    float s = 0.f;
#pragma unroll
    for (int w2 = 0; w2 < 8; ++w2) s += spart[w2][idx];
    const bool valid = (m < NROWS);
    float Z;
    ull key;
    if (valid) {
      float se = sel[m] ? NEGV : s;
      sc[m] = se;
      key = ((ull)fkey(se + gum[m]) << 32) | (unsigned)(NITEMS - m);
      Z = fexp(se);
    } else {
      key = 0;
      Z = 0.f;
    }
#pragma unroll
    for (int off = 32; off > 0; off >>= 1) {
      Z += __shfl_xor(Z, off);
      ull Ko = __shfl_xor(key, off);
      if (Ko > key) key = Ko;
    }
    if (lane == 0) { bZa[g * 2 + w] = Z; bkey[g * 2 + w] = key; }
  }
}

// ---------------- final outputs for step 15 ----------------
__launch_bounds__(256)
__global__ void k_tail(const float* __restrict__ bZa, const ull* __restrict__ bkey,
                       const float* __restrict__ sc, const int* __restrict__ done2,
                       float* __restrict__ outf) {
  __shared__ float redz[256];
  __shared__ ull redk[256];
  const int tid = threadIdx.x;
  float Zl = 0.f;
  ull Kl = 0;
  for (int i = tid; i < NGRP; i += 256) {
    Zl += bZa[i];
    ull k = bkey[i];
    if (k > Kl) Kl = k;
  }
  redz[tid] = Zl;
  redk[tid] = Kl;
  __syncthreads();
  for (int s2 = 128; s2 > 0; s2 >>= 1) {
    if (tid < s2) {
      redz[tid] += redz[tid + s2];
      if (redk[tid + s2] > redk[tid]) redk[tid] = redk[tid + s2];
    }
    __syncthreads();
  }
  if (tid == 0) {
    const float Z = redz[0];
    const ull K = redk[0];
    const int out = NITEMS - (int)(unsigned)(K & 0xffffffffull);
    const int d_in = done2[(TT - 1) & 1];
    outf[TT - 1] = (float)(d_in ? NITEMS : out);
    outf[2 * TT - 1] = d_in ? 0.f : (sc[out] - logf(Z));
  }
}

// ======================================================================
extern "C" void kernel_launch(void* const* d_in, const int* in_sizes, int n_in,
                              void* d_out, int out_size, void* d_ws, size_t ws_size,
                              hipStream_t stream) {
  const float* attn_mem = (const float*)d_in[0];
  const float* stoprow  = (const float*)d_in[1];
  const float* init_h   = (const float*)d_in[2];
  const float* init_c   = (const float*)d_in[3];
  const float* init_i   = (const float*)d_in[4];
  const float* attn_wm  = (const float*)d_in[5];
  const float* attn_wq  = (const float*)d_in[6];
  const float* attn_v   = (const float*)d_in[7];
  const float* hop_wm   = (const float*)d_in[8];
  const float* hop_wq   = (const float*)d_in[9];
  const float* hop_v    = (const float*)d_in[10];
  const float* w_ih     = (const float*)d_in[11];
  const float* w_hh     = (const float*)d_in[12];
  const float* b_ih     = (const float*)d_in[13];
  const float* b_hh     = (const float*)d_in[14];
  const float* gumbel   = (const float*)d_in[15];

  float* ws = (float*)d_ws;
  size_t fo = 0;
  ushort* hop_feat = (ushort*)(ws + fo);   fo += (size_t)NROWS * HH / 2 + 8;  // bf16
  ushort* attn_featT = (ushort*)(ws + fo); fo += (size_t)HH * NP / 2;         // bf16, padded
  float* sc  = ws + fo; fo += 50048;
  int* sel   = (int*)(ws + fo); fo += 50048;
  float* qp  = ws + fo; fo += (size_t)HOPBLK * 512;
  float* bZh = ws + fo; fo += HOPBLK;
  float* bZa = ws + fo; fo += 1024;
  ull* bkey  = (ull*)(ws + fo); fo += 2048;
  float* gates = ws + fo; fo += 4 * HH;
  float* hv  = ws + fo; fo += HH;
  float* cv0 = ws + fo; fo += HH;
  float* cv1 = ws + fo; fo += HH;
  float* b1  = ws + fo; fo += HH;
  float* b2  = ws + fo; fo += HH;
  float* qn  = ws + fo; fo += HH;
  int* done2 = (int*)(ws + fo); fo += 2;
  int* xrow2 = (int*)(ws + fo); fo += 2;
  if (fo * sizeof(float) > ws_size) return;

  float* outf = (float*)d_out;

  k_zero<<<196, 256, 0, stream>>>(sel);
  dim3 ggrid(4, (NP + 127) / 128);  // 391 m-tiles x 4 n-tiles = 1564 blocks
  k_feat_gemm<1><<<ggrid, 256, 0, stream>>>(attn_mem, stoprow, attn_wm, attn_featT);
  k_feat_gemm<0><<<ggrid, 256, 0, stream>>>(attn_mem, stoprow, hop_wm, hop_feat);

  for (int t = 0; t < TT; ++t) {
    k_final_gates<<<512, 256, 0, stream>>>(bZa, bkey, sc, sel, done2, xrow2, outf,
                                           attn_mem, stoprow, init_i, init_h, hv,
                                           w_ih, w_hh, b_ih, b_hh, gates, t);
    k_hc_b1<<<8, 256, 0, stream>>>(gates, init_c, cv0, cv1, hv, hop_wq, b1, t);
    k_hop<<<HOPBLK, 256, 0, stream>>>(hop_feat, b1, hop_v, qp, bZh);
    k_qn<<<16, 1024, 0, stream>>>(qp, bZh, qn);
    k_gemv<<<8, 256, 0, stream>>>(qn, attn_wq, b2);
    k_attnT<<<(NP / 128), 512, 0, stream>>>(attn_featT, b2, attn_v, sel,
                                            gumbel + (size_t)t * NROWS, sc, bZa, bkey);
  }
  k_tail<<<1, 256, 0, stream>>>(bZa, bkey, sc, done2, outf);
}

// Round 10
// 2136.466 us; speedup vs baseline: 3.0851x; 1.1978x over previous
//
#include <hip/hip_runtime.h>
#include <math.h>

#define NITEMS 50000
#define NROWS 50001
#define NP 50048          // padded row count (391*128)
#define DD 512
#define HH 512
#define TT 16
#define NEGV (-1e18f)
#define NGRP 782
#define HOPBLK 2048

typedef unsigned long long ull;
typedef unsigned short ushort;
typedef short short8 __attribute__((ext_vector_type(8)));
typedef float f32x4 __attribute__((ext_vector_type(4)));

// ---- order-preserving float <-> uint key ----
__device__ __forceinline__ unsigned fkey(float f) {
  unsigned u = __float_as_uint(f);
  return (u & 0x80000000u) ? ~u : (u | 0x80000000u);
}

// fast tanh / exp via v_exp_f32 + v_rcp_f32
__device__ __forceinline__ float ftanh(float x) {
  float e = __builtin_amdgcn_exp2f(x * 2.885390081777927f);
  return 1.f - 2.f * __builtin_amdgcn_rcpf(e + 1.f);
}
__device__ __forceinline__ float fexp(float x) {
  return __builtin_amdgcn_exp2f(x * 1.4426950408889634f);
}

// ---- bf16 helpers (RNE) ----
__device__ __forceinline__ ushort rne1(float a) {
  unsigned u = __float_as_uint(a);
  return (ushort)((u + 0x7fffu + ((u >> 16) & 1u)) >> 16);
}
__device__ __forceinline__ float bf2f(ushort h) { return __uint_as_float((unsigned)h << 16); }
__device__ __forceinline__ unsigned pack_bf16(float a, float b) {
  return (unsigned)rne1(a) | ((unsigned)rne1(b) << 16);
}
__device__ __forceinline__ float bflo(unsigned u) { return __uint_as_float(u << 16); }
__device__ __forceinline__ float bfhi(unsigned u) { return __uint_as_float(u & 0xffff0000u); }

// ---- async global->LDS, 16B per lane (LDS dest = wave-uniform base + lane*16) ----
__device__ __forceinline__ void gl_lds16(const void* g, void* l) {
#if __has_builtin(__builtin_amdgcn_global_load_lds)
  __builtin_amdgcn_global_load_lds((const __attribute__((address_space(1))) unsigned*)g,
                                   (__attribute__((address_space(3))) unsigned*)l, 16, 0, 0);
#else
  const int lane = threadIdx.x & 63;
  *(uint4*)((char*)l + lane * 16) = *(const uint4*)g;
#endif
}

#define MFMA(a, b, c) __builtin_amdgcn_mfma_f32_16x16x32_bf16(a, b, c, 0, 0, 0)

// ---------------- A -> (Ahi, Alo) bf16 [NP][512]; row 50000 = stoprow, rows >50000 zero ----
__global__ void k_convA(const float* __restrict__ A0, const float* __restrict__ stoprow,
                        ushort* __restrict__ Ahi, ushort* __restrict__ Alo) {
  const size_t t = (size_t)blockIdx.x * 256 + threadIdx.x;
  const size_t base = t * 8;
  const int row = (int)(base >> 9);
  float v[8];
  if (row < NITEMS) {
    const float4* p = (const float4*)(A0 + base);
    float4 x = p[0], y = p[1];
    v[0] = x.x; v[1] = x.y; v[2] = x.z; v[3] = x.w;
    v[4] = y.x; v[5] = y.y; v[6] = y.z; v[7] = y.w;
  } else if (row == NITEMS) {
    const float4* p = (const float4*)(stoprow + (base & 511));
    float4 x = p[0], y = p[1];
    v[0] = x.x; v[1] = x.y; v[2] = x.z; v[3] = x.w;
    v[4] = y.x; v[5] = y.y; v[6] = y.z; v[7] = y.w;
  } else {
#pragma unroll
    for (int j = 0; j < 8; ++j) v[j] = 0.f;
  }
  unsigned hw[4], lw[4];
#pragma unroll
  for (int j = 0; j < 4; ++j) {
    float a0 = v[2 * j], a1 = v[2 * j + 1];
    ushort h0 = rne1(a0), h1 = rne1(a1);
    hw[j] = (unsigned)h0 | ((unsigned)h1 << 16);
    lw[j] = pack_bf16(a0 - bf2f(h0), a1 - bf2f(h1));
  }
  *(uint4*)(Ahi + base) = make_uint4(hw[0], hw[1], hw[2], hw[3]);
  *(uint4*)(Alo + base) = make_uint4(lw[0], lw[1], lw[2], lw[3]);
}

// ---------------- W [k][n] -> transposed bf16 (WhiT, WloT) [n][k] ----------------
__global__ void k_convBT(const float* __restrict__ W, ushort* __restrict__ WhiT,
                         ushort* __restrict__ WloT) {
  const int n = blockIdx.x;
  const int k0 = threadIdx.x * 2;
  float a0 = W[(size_t)k0 * 512 + n];
  float a1 = W[(size_t)(k0 + 1) * 512 + n];
  ushort h0 = rne1(a0), h1 = rne1(a1);
  *(unsigned*)(WhiT + (size_t)n * 512 + k0) = (unsigned)h0 | ((unsigned)h1 << 16);
  *(unsigned*)(WloT + (size_t)n * 512 + k0) = pack_bf16(a0 - bf2f(h0), a1 - bf2f(h1));
}

// ---------------- MFMA GEMM: C = A@W via bf16x2 split (3 terms), bf16 out ----------------
// 128x128 tile, BK=64, 256 thr / 4 waves, wave tile 64x64 (4x4 frags of 16x16x32).
// LDS tiles [row][128B] with byte-swizzle (row&7)<<4 applied on the GLOBAL source.
template <int TR>
__launch_bounds__(256, 2)
__global__ void k_mfma(const ushort* __restrict__ Ahi, const ushort* __restrict__ Alo,
                       const ushort* __restrict__ BhT, const ushort* __restrict__ BlT,
                       ushort* __restrict__ C) {
  __shared__ __align__(16) char lds[65536];
  char* sA0 = lds;
  char* sA1 = lds + 16384;
  char* sB0 = lds + 32768;
  char* sB1 = lds + 49152;
  const int tid = threadIdx.x;
  const int lane = tid & 63, w = tid >> 6;
  // bijective XCD-chunk swizzle (1564 blocks; q=195, r=4)
  const int lid = blockIdx.y * 4 + blockIdx.x;
  const int xcd = lid & 7, pos = lid >> 3;
  const int orig = ((xcd < 4) ? xcd * 196 : 784 + (xcd - 4) * 195) + pos;
  const int m0 = (orig >> 2) * 128, n0 = (orig & 3) * 128;

  const int aR0 = (w & 1) * 64, bR0 = (w >> 1) * 64;

  f32x4 acc[4][4];
  const f32x4 z4 = {0.f, 0.f, 0.f, 0.f};
#pragma unroll
  for (int i = 0; i < 4; ++i)
#pragma unroll
    for (int j = 0; j < 4; ++j) acc[i][j] = z4;

#define STAGE_ALL(KT)                                                                     \
  {                                                                                       \
    _Pragma("unroll") for (int i = 0; i < 4; ++i) {                                       \
      const int row = i * 32 + (tid >> 3);                                                \
      const int kb = ((tid & 7) << 4) ^ ((row & 7) << 4);                                 \
      const int ldso = i * 4096 + (w << 10);                                              \
      gl_lds16((const char*)(Ahi + ((size_t)(m0 + row) << 9) + (KT)) + kb, sA0 + ldso);   \
      gl_lds16((const char*)(Alo + ((size_t)(m0 + row) << 9) + (KT)) + kb, sA1 + ldso);   \
      gl_lds16((const char*)(BhT + ((size_t)(n0 + row) << 9) + (KT)) + kb, sB0 + ldso);   \
      gl_lds16((const char*)(BlT + ((size_t)(n0 + row) << 9) + (KT)) + kb, sB1 + ldso);   \
    }                                                                                     \
  }

  STAGE_ALL(0)
  __syncthreads();
  for (int c = 0; c < 8; ++c) {
#pragma unroll
    for (int ks = 0; ks < 2; ++ks) {
      short8 ah[4], al[4], bh[4], bl[4];
      const int kbb = ks * 64 + ((lane >> 4) << 4);
#pragma unroll
      for (int f = 0; f < 4; ++f) {
        const int ra = aR0 + f * 16 + (lane & 15);
        const int oa = ra * 128 + (kbb ^ ((ra & 7) << 4));
        ah[f] = *(const short8*)(sA0 + oa);
        al[f] = *(const short8*)(sA1 + oa);
        const int rb = bR0 + f * 16 + (lane & 15);
        const int ob = rb * 128 + (kbb ^ ((rb & 7) << 4));
        bh[f] = *(const short8*)(sB0 + ob);
        bl[f] = *(const short8*)(sB1 + ob);
      }
#pragma unroll
      for (int mf = 0; mf < 4; ++mf)
#pragma unroll
        for (int nf = 0; nf < 4; ++nf) {
          acc[mf][nf] = MFMA(ah[mf], bh[nf], acc[mf][nf]);
          acc[mf][nf] = MFMA(ah[mf], bl[nf], acc[mf][nf]);
          acc[mf][nf] = MFMA(al[mf], bh[nf], acc[mf][nf]);
        }
    }
    if (c < 7) {
      __syncthreads();
      STAGE_ALL((c + 1) * 64)
      __syncthreads();
    }
  }
#undef STAGE_ALL

  // epilogue: C/D frag layout col=lane&15, row=(lane>>4)*4+reg  [verified m89]
#pragma unroll
  for (int mf = 0; mf < 4; ++mf)
#pragma unroll
    for (int nf = 0; nf < 4; ++nf) {
      const f32x4 a = acc[mf][nf];
      const int n = n0 + bR0 + nf * 16 + (lane & 15);
      const int mb = m0 + aR0 + mf * 16 + ((lane >> 4) << 2);
      if (TR) {
        ushort* p = C + (size_t)n * NP + mb;   // featT[n][m], 4 consecutive m
        *(uint2*)p = make_uint2(pack_bf16(a.x, a.y), pack_bf16(a.z, a.w));
      } else {
        C[(size_t)(mb + 0) * 512 + n] = rne1(a.x);
        C[(size_t)(mb + 1) * 512 + n] = rne1(a.y);
        C[(size_t)(mb + 2) * 512 + n] = rne1(a.z);
        C[(size_t)(mb + 3) * 512 + n] = rne1(a.w);
      }
    }
}

// ---------------- zero sel ----------------
__global__ void k_zero(int* __restrict__ sel) {
  int i = blockIdx.x * 256 + threadIdx.x;
  if (i < NROWS) sel[i] = 0;
}

// ---------------- finalize prev step (redundant in all blocks) + LSTM gates ----------------
__launch_bounds__(256)
__global__ void k_final_gates(const float* __restrict__ bZa, const ull* __restrict__ bkey,
                              const float* __restrict__ sc,
                              int* __restrict__ sel, int* __restrict__ done2,
                              int* __restrict__ xrow2, float* __restrict__ outf,
                              const float* __restrict__ attn_mem, const float* __restrict__ stoprow,
                              const float* __restrict__ init_i, const float* __restrict__ init_h,
                              const float* __restrict__ hv,
                              const float* __restrict__ w_ih, const float* __restrict__ w_hh,
                              const float* __restrict__ b_ih, const float* __restrict__ b_hh,
                              float* __restrict__ gates, int t) {
  __shared__ float redz[256];
  __shared__ ull redk[256];
  const int tid = threadIdx.x, blk = blockIdx.x;
  const int w = tid >> 6, lane = tid & 63;
  int xrow = -1;
  if (t > 0) {
    float Zl = 0.f;
    ull Kl = 0;
    for (int i = tid; i < NGRP; i += 256) {
      Zl += bZa[i];
      ull k = bkey[i];
      if (k > Kl) Kl = k;
    }
    redz[tid] = Zl;
    redk[tid] = Kl;
    __syncthreads();
    for (int s2 = 128; s2 > 0; s2 >>= 1) {
      if (tid < s2) {
        redz[tid] += redz[tid + s2];
        if (redk[tid + s2] > redk[tid]) redk[tid] = redk[tid + s2];
      }
      __syncthreads();
    }
    const float Z = redz[0];
    const ull K = redk[0];
    const int out = NITEMS - (int)(unsigned)(K & 0xffffffffull);
    const int d_in = (t == 1) ? 0 : done2[(t - 1) & 1];
    const int xprev = (t == 1) ? -1 : xrow2[(t - 1) & 1];
    const int nd = d_in | (out == NITEMS);
    xrow = nd ? xprev : out;
    if (blk == 0 && tid == 0) {
      outf[t - 1] = (float)(d_in ? NITEMS : out);
      outf[TT + t - 1] = d_in ? 0.f : (sc[out] - logf(Z));
      if (!d_in) sel[out] = 1;
      done2[t & 1] = nd;
      xrow2[t & 1] = xrow;
    }
  }
  const int r = blk * 4 + w;
  const float* xp = (xrow < 0) ? init_i
                               : ((xrow == NITEMS) ? stoprow : attn_mem + (size_t)xrow * DD);
  const float* hp = (t == 0) ? init_h : hv;
  const float4* x4 = (const float4*)xp;
  const float4* h4 = (const float4*)hp;
  const float4* wi = (const float4*)(w_ih + (size_t)r * DD);
  const float4* wh = (const float4*)(w_hh + (size_t)r * DD);
  float s = 0.f;
  float4 a, ww;
  a = x4[lane * 2];     ww = wi[lane * 2];     s += a.x * ww.x + a.y * ww.y + a.z * ww.z + a.w * ww.w;
  a = x4[lane * 2 + 1]; ww = wi[lane * 2 + 1]; s += a.x * ww.x + a.y * ww.y + a.z * ww.z + a.w * ww.w;
  a = h4[lane * 2];     ww = wh[lane * 2];     s += a.x * ww.x + a.y * ww.y + a.z * ww.z + a.w * ww.w;
  a = h4[lane * 2 + 1]; ww = wh[lane * 2 + 1]; s += a.x * ww.x + a.y * ww.y + a.z * ww.z + a.w * ww.w;
#pragma unroll
  for (int off = 32; off > 0; off >>= 1) s += __shfl_xor(s, off);
  if (lane == 0) gates[r] = s + b_ih[r] + b_hh[r];
}

// ---------------- h,c update (redundant x8) + b1 = h @ hop_wq ----------------
__launch_bounds__(256)
__global__ void k_hc_b1(const float* __restrict__ gates, const float* __restrict__ init_c,
                        float* __restrict__ cv0, float* __restrict__ cv1, float* __restrict__ hv,
                        const float* __restrict__ hop_wq, float* __restrict__ b1, int t) {
  __shared__ float h[512];
  __shared__ float red[256];
  const int tid = threadIdx.x, blk = blockIdx.x;
  const float* csrc = (t == 0) ? init_c : ((t & 1) ? cv1 : cv0);
  float* cdst = (t & 1) ? cv0 : cv1;
  for (int i = tid; i < 512; i += 256) {
    float gi = gates[i], gf = gates[512 + i], gg = gates[1024 + i], go = gates[1536 + i];
    float si = 1.f / (1.f + expf(-gi));
    float sf = 1.f / (1.f + expf(-gf));
    float so = 1.f / (1.f + expf(-go));
    float cn = sf * csrc[i] + si * tanhf(gg);
    float hval = so * tanhf(cn);
    h[i] = hval;
    if (blk == 0) { cdst[i] = cn; hv[i] = hval; }
  }
  __syncthreads();
  const int cc = tid & 63, q = tid >> 6;
  const int j = blk * 64 + cc;
  float pb = 0.f;
  for (int i = q * 128; i < q * 128 + 128; ++i) pb = fmaf(h[i], hop_wq[(size_t)i * HH + j], pb);
  red[tid] = pb;
  __syncthreads();
  if (tid < 64) b1[blk * 64 + tid] = red[tid] + red[tid + 64] + red[tid + 128] + red[tid + 192];
}

// ---------------- hop: fused score + softmax-weighted sum over bf16 feat ----------------
__launch_bounds__(256)
__global__ void k_hop(const ushort* __restrict__ feat, const float* __restrict__ bvec,
                      const float* __restrict__ v, float* __restrict__ qp,
                      float* __restrict__ bZh) {
  __shared__ float sz[4];
  __shared__ float qbuf[4][512];
  const int tid = threadIdx.x, blk = blockIdx.x;
  const int w = tid >> 6, lane = tid & 63;
  const int wv = blk * 4 + w;
  float bv[8], vv[8], qa[8];
#pragma unroll
  for (int j = 0; j < 8; ++j) { bv[j] = bvec[lane * 8 + j]; vv[j] = v[lane * 8 + j]; qa[j] = 0.f; }
  float Z = 0.f;
  for (int m = wv; m < NROWS; m += 4 * HOPBLK) {
    const uint4* fp = (const uint4*)(feat + (size_t)m * HH);
    uint4 U = fp[lane];
    float f[8] = {bflo(U.x), bfhi(U.x), bflo(U.y), bfhi(U.y),
                  bflo(U.z), bfhi(U.z), bflo(U.w), bfhi(U.w)};
    float s = 0.f;
#pragma unroll
    for (int j = 0; j < 8; ++j) s += ftanh(f[j] + bv[j]) * vv[j];
#pragma unroll
    for (int off = 32; off > 0; off >>= 1) s += __shfl_xor(s, off);
    const float e = fexp(s);
    Z += e;
#pragma unroll
    for (int j = 0; j < 8; ++j) qa[j] = fmaf(e, f[j], qa[j]);
  }
  if (lane == 0) sz[w] = Z;
#pragma unroll
  for (int j = 0; j < 8; ++j) qbuf[w][lane * 8 + j] = qa[j];
  __syncthreads();
  float a0 = 0.f, a1 = 0.f;
#pragma unroll
  for (int w2 = 0; w2 < 4; ++w2) { a0 += qbuf[w2][tid]; a1 += qbuf[w2][tid + 256]; }
  qp[(size_t)blk * 512 + tid] = a0;
  qp[(size_t)blk * 512 + tid + 256] = a1;
  if (tid == 0) bZh[blk] = sz[0] + sz[1] + sz[2] + sz[3];
}

// ---------------- combine 2048 hop partials -> qn ----------------
__launch_bounds__(1024)
__global__ void k_qn(const float* __restrict__ qp, const float* __restrict__ bZh,
                     float* __restrict__ qn) {
  __shared__ float red[1024];
  const int tid = threadIdx.x;
  red[tid] = bZh[tid] + bZh[tid + 1024];
  __syncthreads();
  for (int s2 = 512; s2 > 0; s2 >>= 1) {
    if (tid < s2) red[tid] += red[tid + s2];
    __syncthreads();
  }
  const float Z = red[0];
  __syncthreads();
  const int cc = tid & 31, q = tid >> 5;
  const int col = blockIdx.x * 32 + cc;
  float acc = 0.f;
  for (int p = q * 64; p < q * 64 + 64; ++p) acc += qp[(size_t)p * 512 + col];
  red[tid] = acc;
  __syncthreads();
  if (tid < 32) {
    float a = 0.f;
#pragma unroll
    for (int g = 0; g < 32; ++g) a += red[tid + 32 * g];
    qn[blockIdx.x * 32 + tid] = a / Z;
  }
}

// ---------------- b2[j] = sum_i qn[i] * W[i][j] ----------------
__launch_bounds__(256)
__global__ void k_gemv(const float* __restrict__ q, const float* __restrict__ W,
                       float* __restrict__ out) {
  __shared__ float lds[256];
  const int tid = threadIdx.x;
  const int cc = tid & 63, rs = tid >> 6;
  const int j = blockIdx.x * 64 + cc;
  float p = 0.f;
  for (int i = rs * 128; i < rs * 128 + 128; ++i) p += q[i] * W[(size_t)i * HH + j];
  lds[tid] = p;
  __syncthreads();
  if (tid < 64) out[blockIdx.x * 64 + tid] = lds[tid] + lds[tid + 64] + lds[tid + 128] + lds[tid + 192];
}

// ---------------- attn: bf16 transposed sweep ----------------
__launch_bounds__(512)
__global__ void k_attnT(const ushort* __restrict__ featT, const float* __restrict__ b2,
                        const float* __restrict__ av, const int* __restrict__ sel,
                        const float* __restrict__ gum, float* __restrict__ sc,
                        float* __restrict__ bZa, ull* __restrict__ bkey) {
  __shared__ float spart[8][128];
  const int tid = threadIdx.x, g = blockIdx.x;
  const int w = tid >> 6, lane = tid & 63;
  const int mb = g * 128 + lane * 2;
  const int h0 = w * 64;
  const ushort* fp = featT + (size_t)h0 * NP + mb;
  float acc0 = 0.f, acc1 = 0.f;
#pragma unroll 8
  for (int hh = 0; hh < 64; ++hh) {
    const unsigned u = *(const unsigned*)fp;
    fp += NP;
    const float bb = b2[h0 + hh], vv = av[h0 + hh];
    acc0 += ftanh(bflo(u) + bb) * vv;
    acc1 += ftanh(bfhi(u) + bb) * vv;
  }
  spart[w][lane * 2] = acc0;
  spart[w][lane * 2 + 1] = acc1;
  __syncthreads();
  if (w < 2) {
    const int idx = w * 64 + lane;
    const int m = g * 128 + idx;
    float s = 0.f;
#pragma unroll
    for (int w2 = 0; w2 < 8; ++w2) s += spart[w2][idx];
    const bool valid = (m < NROWS);
    float Z;
    ull key;
    if (valid) {
      float se = sel[m] ? NEGV : s;
      sc[m] = se;
      key = ((ull)fkey(se + gum[m]) << 32) | (unsigned)(NITEMS - m);
      Z = fexp(se);
    } else {
      key = 0;
      Z = 0.f;
    }
#pragma unroll
    for (int off = 32; off > 0; off >>= 1) {
      Z += __shfl_xor(Z, off);
      ull Ko = __shfl_xor(key, off);
      if (Ko > key) key = Ko;
    }
    if (lane == 0) { bZa[g * 2 + w] = Z; bkey[g * 2 + w] = key; }
  }
}

// ---------------- final outputs for step 15 ----------------
__launch_bounds__(256)
__global__ void k_tail(const float* __restrict__ bZa, const ull* __restrict__ bkey,
                       const float* __restrict__ sc, const int* __restrict__ done2,
                       float* __restrict__ outf) {
  __shared__ float redz[256];
  __shared__ ull redk[256];
  const int tid = threadIdx.x;
  float Zl = 0.f;
  ull Kl = 0;
  for (int i = tid; i < NGRP; i += 256) {
    Zl += bZa[i];
    ull k = bkey[i];
    if (k > Kl) Kl = k;
  }
  redz[tid] = Zl;
  redk[tid] = Kl;
  __syncthreads();
  for (int s2 = 128; s2 > 0; s2 >>= 1) {
    if (tid < s2) {
      redz[tid] += redz[tid + s2];
      if (redk[tid + s2] > redk[tid]) redk[tid] = redk[tid + s2];
    }
    __syncthreads();
  }
  if (tid == 0) {
    const float Z = redz[0];
    const ull K = redk[0];
    const int out = NITEMS - (int)(unsigned)(K & 0xffffffffull);
    const int d_in = done2[(TT - 1) & 1];
    outf[TT - 1] = (float)(d_in ? NITEMS : out);
    outf[2 * TT - 1] = d_in ? 0.f : (sc[out] - logf(Z));
  }
}

// ======================================================================
extern "C" void kernel_launch(void* const* d_in, const int* in_sizes, int n_in,
                              void* d_out, int out_size, void* d_ws, size_t ws_size,
                              hipStream_t stream) {
  const float* attn_mem = (const float*)d_in[0];
  const float* stoprow  = (const float*)d_in[1];
  const float* init_h   = (const float*)d_in[2];
  const float* init_c   = (const float*)d_in[3];
  const float* init_i   = (const float*)d_in[4];
  const float* attn_wm  = (const float*)d_in[5];
  const float* attn_wq  = (const float*)d_in[6];
  const float* attn_v   = (const float*)d_in[7];
  const float* hop_wm   = (const float*)d_in[8];
  const float* hop_wq   = (const float*)d_in[9];
  const float* hop_v    = (const float*)d_in[10];
  const float* w_ih     = (const float*)d_in[11];
  const float* w_hh     = (const float*)d_in[12];
  const float* b_ih     = (const float*)d_in[13];
  const float* b_hh     = (const float*)d_in[14];
  const float* gumbel   = (const float*)d_in[15];

  float* ws = (float*)d_ws;
  size_t fo = 0;
  const size_t FB = (size_t)NP * 512 / 2;  // bf16 matrix in float units
  ushort* hop_feat   = (ushort*)(ws + fo); fo += FB;
  ushort* attn_featT = (ushort*)(ws + fo); fo += FB;
  ushort* Ahi = (ushort*)(ws + fo); fo += FB;
  ushort* Alo = (ushort*)(ws + fo); fo += FB;
  ushort* WhiT_a = (ushort*)(ws + fo); fo += 131072;
  ushort* WloT_a = (ushort*)(ws + fo); fo += 131072;
  ushort* WhiT_h = (ushort*)(ws + fo); fo += 131072;
  ushort* WloT_h = (ushort*)(ws + fo); fo += 131072;
  float* sc  = ws + fo; fo += 50048;
  int* sel   = (int*)(ws + fo); fo += 50048;
  float* qp  = ws + fo; fo += (size_t)HOPBLK * 512;
  float* bZh = ws + fo; fo += HOPBLK;
  float* bZa = ws + fo; fo += 1024;
  ull* bkey  = (ull*)(ws + fo); fo += 2048;
  float* gates = ws + fo; fo += 4 * HH;
  float* hv  = ws + fo; fo += HH;
  float* cv0 = ws + fo; fo += HH;
  float* cv1 = ws + fo; fo += HH;
  float* b1  = ws + fo; fo += HH;
  float* b2  = ws + fo; fo += HH;
  float* qn  = ws + fo; fo += HH;
  int* done2 = (int*)(ws + fo); fo += 2;
  int* xrow2 = (int*)(ws + fo); fo += 2;
  if (fo * sizeof(float) > ws_size) return;

  float* outf = (float*)d_out;

  k_convA<<<(NP * 512 / 8) / 256, 256, 0, stream>>>(attn_mem, stoprow, Ahi, Alo);
  k_convBT<<<512, 256, 0, stream>>>(attn_wm, WhiT_a, WloT_a);
  k_convBT<<<512, 256, 0, stream>>>(hop_wm, WhiT_h, WloT_h);
  k_zero<<<196, 256, 0, stream>>>(sel);

  dim3 ggrid(4, NP / 128);  // 1564 blocks
  k_mfma<1><<<ggrid, 256, 0, stream>>>(Ahi, Alo, WhiT_a, WloT_a, attn_featT);
  k_mfma<0><<<ggrid, 256, 0, stream>>>(Ahi, Alo, WhiT_h, WloT_h, hop_feat);

  for (int t = 0; t < TT; ++t) {
    k_final_gates<<<512, 256, 0, stream>>>(bZa, bkey, sc, sel, done2, xrow2, outf,
                                           attn_mem, stoprow, init_i, init_h, hv,
                                           w_ih, w_hh, b_ih, b_hh, gates, t);
    k_hc_b1<<<8, 256, 0, stream>>>(gates, init_c, cv0, cv1, hv, hop_wq, b1, t);
    k_hop<<<HOPBLK, 256, 0, stream>>>(hop_feat, b1, hop_v, qp, bZh);
    k_qn<<<16, 1024, 0, stream>>>(qp, bZh, qn);
    k_gemv<<<8, 256, 0, stream>>>(qn, attn_wq, b2);
    k_attnT<<<(NP / 128), 512, 0, stream>>>(attn_featT, b2, attn_v, sel,
                                            gumbel + (size_t)t * NROWS, sc, bZa, bkey);
  }
  k_tail<<<1, 256, 0, stream>>>(bZa, bkey, sc, done2, outf);
}